// Round 2
// baseline (347.392 us; speedup 1.0000x reference)
//
#include <hip/hip_runtime.h>
#include <hip/hip_bf16.h>
#include <math.h>

// Problem constants: B=4, T=4096, C=1024, H=16, D=64, BLOCK=128
//   M = B*T = 16384 rows
//   GEMM1: [16384,1024] @ [1024,3072] -> qkv
//   attn : 2048 blocks of (128x64) q,k,v, causal-within-block softmax
//   GEMM2: [16384,1024] @ [1024,1024] + bias -> out (fp32)

typedef __bf16 bf16_t;
typedef __bf16 bf16x8 __attribute__((ext_vector_type(8)));
typedef float  f32x4  __attribute__((ext_vector_type(4)));

typedef const __attribute__((address_space(1))) void* gptr_t;
typedef __attribute__((address_space(3))) void* lptr_t;

// ---------------------------------------------------------------- cvt: f32 -> bf16
__global__ __launch_bounds__(256) void cvt_f32_bf16(const float* __restrict__ in,
                                                    bf16_t* __restrict__ out, size_t n) {
    size_t stride = (size_t)gridDim.x * blockDim.x * 4;
    for (size_t i = ((size_t)blockIdx.x * blockDim.x + threadIdx.x) * 4; i < n; i += stride) {
        float4 v = *(const float4*)(in + i);
        bf16_t t[4];
        t[0] = (bf16_t)v.x; t[1] = (bf16_t)v.y; t[2] = (bf16_t)v.z; t[3] = (bf16_t)v.w;
        *(uint2*)(out + i) = *(uint2*)t;
    }
}

// ------------------------------- transpose+cvt: W[K][N] fp32 -> Wt[N][K] bf16, LDS-tiled
__global__ __launch_bounds__(256) void transpose_cvt(const float* __restrict__ in,
                                                     bf16_t* __restrict__ out, int K, int N) {
    __shared__ float tile[32][33];
    const int tx = threadIdx.x & 31, ty = threadIdx.x >> 5;   // 32 x 8
    const int bx = blockIdx.x, by = blockIdx.y;               // N/32, K/32
    #pragma unroll
    for (int i = 0; i < 4; i++) {
        const int k = by * 32 + ty + i * 8;
        tile[ty + i * 8][tx] = in[(size_t)k * N + bx * 32 + tx];
    }
    __syncthreads();
    #pragma unroll
    for (int i = 0; i < 4; i++) {
        const int n = bx * 32 + ty + i * 8;
        out[(size_t)n * K + by * 32 + tx] = (bf16_t)tile[tx][ty + i * 8];
    }
}

// ---------------------------------------------------------------- GEMM (B-transposed)
// C[M][N] = A[M][K] * Bt[N][K]^T   (bf16 in, fp32 accum)
// 256x256 tile, 8 waves (2Mx4N), ring of 4 K=32 slices per matrix (128 KiB LDS).
// Per slice: counted s_waitcnt vmcnt(8) [never 0 in steady state], ONE s_barrier,
// stage slice ks+3 (4 global_load_lds/wave), 12 swizzled ds_read_b128 (af[8],bf[4]),
// setprio(1) + 32 MFMA + setprio(0).  Prefetch depth 3 slices covers L2/HBM latency.
// LDS swizzle (rule 21, both-sides): 16B chunk ^= (row>>1)&3, applied on the
// pre-swizzled GLOBAL source addr (global_load_lds dest must stay linear) and on
// the ds_read addr. Fragment row-bases are 0 mod 8, so the read key is (l16>>1)&3.
template <bool BF16_OUT, bool BIAS>
__global__ __launch_bounds__(512, 2) void gemm256(const bf16_t* __restrict__ A,
                                                  const bf16_t* __restrict__ Bt,
                                                  void* __restrict__ Cout,
                                                  const float* __restrict__ bias,
                                                  int M, int N, int K) {
    __shared__ bf16_t As[4][256 * 32];   // ring slot s: rows 0..255, K-slice of 32
    __shared__ bf16_t Bs[4][256 * 32];

    const int tid  = threadIdx.x;
    const int lane = tid & 63, wave = tid >> 6;
    const int quad = lane >> 4, l16 = lane & 15;
    const int wm = wave >> 2, wn = wave & 3;   // 2 x 4 wave grid; wave owns 128x64 of C
    const int bn = blockIdx.x, bm = blockIdx.y;

    const bf16_t* Ab = A  + (size_t)bm * 256 * K;
    const bf16_t* Bb = Bt + (size_t)bn * 256 * K;

    // staging geometry: wave-load = 16 rows x 64B; lane -> (row = l>>2, chunk = l&3)
    const int srow = lane >> 2;
    const int scs  = (lane & 3) ^ ((srow >> 1) & 3);   // pre-swizzled src chunk
    const int csw  = (l16 >> 1) & 3;                   // read-side swizzle key

    f32x4 acc[8][4];
    #pragma unroll
    for (int i = 0; i < 8; ++i)
        #pragma unroll
        for (int j = 0; j < 4; ++j) acc[i][j] = (f32x4){0.f, 0.f, 0.f, 0.f};

#define STG(ARR, SRC, SLOT, SLICE, I)                                                 \
    __builtin_amdgcn_global_load_lds(                                                 \
        (gptr_t)((SRC) + (size_t)(wave * 32 + (I) * 16 + srow) * K + (SLICE) * 32 +   \
                 scs * 8),                                                            \
        (lptr_t)&(ARR)[SLOT][(wave * 32 + (I) * 16) * 32], 16, 0, 0)

#define STAGE4(SLICE)                                                                 \
    do {                                                                              \
        const int sl_ = (SLICE) & 3;                                                  \
        STG(As, Ab, sl_, SLICE, 0); STG(As, Ab, sl_, SLICE, 1);                       \
        STG(Bs, Bb, sl_, SLICE, 0); STG(Bs, Bb, sl_, SLICE, 1);                       \
    } while (0)

#define COMPUTE(KS)                                                                   \
    do {                                                                              \
        const bf16_t* Asl_ = As[(KS) & 3];                                            \
        const bf16_t* Bsl_ = Bs[(KS) & 3];                                            \
        bf16x8 af_[8], bf_[4];                                                        \
        _Pragma("unroll")                                                             \
        for (int fr = 0; fr < 8; ++fr)                                                \
            af_[fr] = *(const bf16x8*)&Asl_[(wm * 128 + fr * 16 + l16) * 32 +         \
                                            ((quad ^ csw) << 3)];                     \
        _Pragma("unroll")                                                             \
        for (int fr = 0; fr < 4; ++fr)                                                \
            bf_[fr] = *(const bf16x8*)&Bsl_[(wn * 64 + fr * 16 + l16) * 32 +          \
                                            ((quad ^ csw) << 3)];                     \
        __builtin_amdgcn_s_setprio(1);                                                \
        _Pragma("unroll")                                                             \
        for (int mr = 0; mr < 8; ++mr)                                                \
            _Pragma("unroll")                                                         \
            for (int nr = 0; nr < 4; ++nr)                                            \
                acc[mr][nr] = __builtin_amdgcn_mfma_f32_16x16x32_bf16(                \
                    af_[mr], bf_[nr], acc[mr][nr], 0, 0, 0);                          \
        __builtin_amdgcn_s_setprio(0);                                                \
    } while (0)

    // prologue: stage slices 0,1,2 into slots 0,1,2 (12 loads/wave in flight)
    #pragma unroll
    for (int s = 0; s < 3; ++s) STAGE4(s);

    const int NS = K >> 5;   // K=1024 -> 32 slices
    for (int ks = 0; ks < NS - 3; ++ks) {
        asm volatile("s_waitcnt vmcnt(8)" ::: "memory");  // slice ks landed; 2 slices fly
        __builtin_amdgcn_s_barrier();
        STAGE4(ks + 3);            // overwrites slot (ks-1)&3, safe after barrier
        COMPUTE(ks);
    }
    {   // tail: drain progressively (only place vmcnt reaches 0)
        asm volatile("s_waitcnt vmcnt(8)" ::: "memory");
        __builtin_amdgcn_s_barrier();
        COMPUTE(NS - 3);
        asm volatile("s_waitcnt vmcnt(4)" ::: "memory");
        __builtin_amdgcn_s_barrier();
        COMPUTE(NS - 2);
        asm volatile("s_waitcnt vmcnt(0)" ::: "memory");
        __builtin_amdgcn_s_barrier();
        COMPUTE(NS - 1);
    }
#undef COMPUTE
#undef STAGE4
#undef STG

    // epilogue: C/D layout col=lane&15, row=quad*4+reg
    #pragma unroll
    for (int mr = 0; mr < 8; ++mr) {
        #pragma unroll
        for (int nr = 0; nr < 4; ++nr) {
            const int gcol = bn * 256 + wn * 64 + nr * 16 + l16;
            #pragma unroll
            for (int reg = 0; reg < 4; ++reg) {
                const int grow = bm * 256 + wm * 128 + mr * 16 + quad * 4 + reg;
                float v = acc[mr][nr][reg];
                if (BIAS) v += bias[gcol];
                if (BF16_OUT)
                    ((bf16_t*)Cout)[(size_t)grow * N + gcol] = (bf16_t)v;
                else
                    ((float*)Cout)[(size_t)grow * N + gcol] = v;
            }
        }
    }
}

// ---------------------------------------------------------------- block-local attention
// One workgroup per (b, blk, h). q,k: [128][72] LDS; v stored TRANSPOSED [64][136] so
// PV B-fragments are ds_read_b128. LDS total 54272 B -> 3 blocks/CU.
__global__ __launch_bounds__(256, 3) void attn_kernel(const bf16_t* __restrict__ qkv,
                                                      bf16_t* __restrict__ attn_out) {
    __shared__ __align__(16) char smem[54272];
    bf16_t* qs = (bf16_t*)smem;                   // [128][72]
    bf16_t* ks = (bf16_t*)(smem + 18432);         // [128][72]
    bf16_t* vT = (bf16_t*)(smem + 36864);         // [64][136]  vT[c][r] = v[r][c]
    bf16_t* ps = (bf16_t*)smem;                   // [128][136] overlays qs+ks (34816 <= 36864)

    const int tid = threadIdx.x;
    const int lane = tid & 63, wave = tid >> 6;
    const int quad = lane >> 4, l16 = lane & 15;

    const int bid = blockIdx.x;
    const int h = bid & 15;
    const int blk = (bid >> 4) & 31;
    const int b = bid >> 9;
    const int row0 = (b * 32 + blk) * 128;   // row base in [16384]
    const int LDQ = 3072;

    // ---- stage q,k (vector), v transposed (scalar scatter, one-time)
    for (int t = tid; t < 128 * 8; t += 256) {
        const int r = t >> 3;
        const int c = (t & 7) * 8;           // element offset
        const bf16_t* src = qkv + (size_t)(row0 + r) * LDQ + h * 64;
        *(uint4*)&qs[r * 72 + c] = *(const uint4*)(src + c);
        *(uint4*)&ks[r * 72 + c] = *(const uint4*)(src + 1024 + c);
        bf16x8 vv = *(const bf16x8*)(src + 2048 + c);
        #pragma unroll
        for (int j = 0; j < 8; j++)
            vT[(c + j) * 136 + r] = vv[j];
    }
    __syncthreads();

    // ---- S = q k^T / 8 : wave handles rows [wave*32, wave*32+32) x 128 cols
    f32x4 sfrag[2][8];
    for (int mr = 0; mr < 2; mr++)
        for (int nc = 0; nc < 8; nc++)
            sfrag[mr][nc] = (f32x4){0.f, 0.f, 0.f, 0.f};

    #pragma unroll
    for (int ksl = 0; ksl < 2; ksl++) {     // K=64 in two slices of 32
        bf16x8 aq[2], bk[8];
        #pragma unroll
        for (int mr = 0; mr < 2; mr++)
            aq[mr] = *(const bf16x8*)&qs[(wave * 32 + mr * 16 + l16) * 72 + ksl * 32 + quad * 8];
        #pragma unroll
        for (int nc = 0; nc < 8; nc++)
            bk[nc] = *(const bf16x8*)&ks[(nc * 16 + l16) * 72 + ksl * 32 + quad * 8];
        #pragma unroll
        for (int mr = 0; mr < 2; mr++)
            #pragma unroll
            for (int nc = 0; nc < 8; nc++)
                sfrag[mr][nc] = __builtin_amdgcn_mfma_f32_16x16x32_bf16(aq[mr], bk[nc], sfrag[mr][nc], 0, 0, 0);
    }

    // ---- scale + causal mask (C-layout: row=quad*4+reg, col=nc*16+l16)
    #pragma unroll
    for (int mr = 0; mr < 2; mr++) {
        #pragma unroll
        for (int nc = 0; nc < 8; nc++) {
            #pragma unroll
            for (int reg = 0; reg < 4; reg++) {
                const int row = wave * 32 + mr * 16 + quad * 4 + reg;
                const int col = nc * 16 + l16;
                float s = sfrag[mr][nc][reg] * 0.125f;
                if (col > row) s = -INFINITY;
                sfrag[mr][nc][reg] = s;
            }
        }
    }

    // ---- softmax per row (reduce across 16 lanes of the row-group + 8 col frags)
    #pragma unroll
    for (int mr = 0; mr < 2; mr++) {
        #pragma unroll
        for (int reg = 0; reg < 4; reg++) {
            float m = -INFINITY;
            #pragma unroll
            for (int nc = 0; nc < 8; nc++) m = fmaxf(m, sfrag[mr][nc][reg]);
            #pragma unroll
            for (int off = 1; off < 16; off <<= 1) m = fmaxf(m, __shfl_xor(m, off));
            float sum = 0.f;
            #pragma unroll
            for (int nc = 0; nc < 8; nc++) {
                float e = __expf(sfrag[mr][nc][reg] - m);
                sfrag[mr][nc][reg] = e;
                sum += e;
            }
            #pragma unroll
            for (int off = 1; off < 16; off <<= 1) sum += __shfl_xor(sum, off);
            const float inv = 1.0f / (sum + 1e-6f);
            #pragma unroll
            for (int nc = 0; nc < 8; nc++) sfrag[mr][nc][reg] *= inv;
        }
    }

    __syncthreads();   // all waves done reading qs/ks before P overlays them

    // ---- write P (bf16) to LDS [128][136]
    #pragma unroll
    for (int mr = 0; mr < 2; mr++)
        #pragma unroll
        for (int nc = 0; nc < 8; nc++)
            #pragma unroll
            for (int reg = 0; reg < 4; reg++) {
                const int row = wave * 32 + mr * 16 + quad * 4 + reg;
                const int col = nc * 16 + l16;
                ps[row * 136 + col] = (bf16_t)sfrag[mr][nc][reg];
            }
    __syncthreads();

    // ---- O = P @ V : rows [wave*32, +32) x 64 cols, K=128 in 4 slices; V from vT (b128)
    f32x4 oacc[2][4];
    for (int mr = 0; mr < 2; mr++)
        for (int nd = 0; nd < 4; nd++)
            oacc[mr][nd] = (f32x4){0.f, 0.f, 0.f, 0.f};

    #pragma unroll
    for (int ksl = 0; ksl < 4; ksl++) {
        bf16x8 ap[2];
        #pragma unroll
        for (int mr = 0; mr < 2; mr++)
            ap[mr] = *(const bf16x8*)&ps[(wave * 32 + mr * 16 + l16) * 136 + ksl * 32 + quad * 8];
        #pragma unroll
        for (int nd = 0; nd < 4; nd++) {
            bf16x8 bv = *(const bf16x8*)&vT[(nd * 16 + l16) * 136 + ksl * 32 + quad * 8];
            #pragma unroll
            for (int mr = 0; mr < 2; mr++)
                oacc[mr][nd] = __builtin_amdgcn_mfma_f32_16x16x32_bf16(ap[mr], bv, oacc[mr][nd], 0, 0, 0);
        }
    }

    // ---- store O bf16 into attn buffer [16384][1024]
    #pragma unroll
    for (int mr = 0; mr < 2; mr++)
        #pragma unroll
        for (int nd = 0; nd < 4; nd++)
            #pragma unroll
            for (int reg = 0; reg < 4; reg++) {
                const int row = row0 + wave * 32 + mr * 16 + quad * 4 + reg;
                const int col = h * 64 + nd * 16 + l16;
                attn_out[(size_t)row * 1024 + col] = (bf16_t)oacc[mr][nd][reg];
            }
}

// ---------------------------------------------------------------- launch
extern "C" void kernel_launch(void* const* d_in, const int* in_sizes, int n_in,
                              void* d_out, int out_size, void* d_ws, size_t ws_size,
                              hipStream_t stream) {
    const float* x     = (const float*)d_in[0];   // [4,4096,1024]
    const float* Wqkv  = (const float*)d_in[1];   // [1024,3072]
    const float* Wproj = (const float*)d_in[2];   // [1024,1024]
    const float* bproj = (const float*)d_in[3];   // [1024]

    const int M = 16384, C = 1024, N1 = 3072;

    // workspace carve (bytes): all 16B aligned
    char* ws = (char*)d_ws;
    bf16_t* xb     = (bf16_t*)(ws);                                   // 32 MB
    bf16_t* wqkvT  = (bf16_t*)(ws + 33554432);                        //  6 MB  [3072][1024]
    bf16_t* wprojT = (bf16_t*)(ws + 39845888);                        //  2 MB  [1024][1024]
    bf16_t* qkvb   = (bf16_t*)(ws + 41943040);                        // 96 MB  [16384][3072]
    bf16_t* attnb  = (bf16_t*)(ws + 142606336);                       // 32 MB  [16384][1024]
    // total 168 MB

    cvt_f32_bf16<<<8192, 256, 0, stream>>>(x, xb, (size_t)M * C);
    transpose_cvt<<<dim3(N1 / 32, C / 32), 256, 0, stream>>>(Wqkv, wqkvT, C, N1);
    transpose_cvt<<<dim3(C / 32, C / 32), 256, 0, stream>>>(Wproj, wprojT, C, C);

    gemm256<true, false><<<dim3(N1 / 256, M / 256), 512, 0, stream>>>(
        xb, wqkvT, (void*)qkvb, nullptr, M, N1, C);

    attn_kernel<<<2048, 256, 0, stream>>>(qkvb, attnb);

    gemm256<false, true><<<dim3(C / 256, M / 256), 512, 0, stream>>>(
        attnb, wprojT, d_out, bproj, M, C, C);
}

// Round 3
// 321.709 us; speedup vs baseline: 1.0798x; 1.0798x over previous
//
#include <hip/hip_runtime.h>
#include <hip/hip_bf16.h>
#include <math.h>

// Problem constants: B=4, T=4096, C=1024, H=16, D=64, BLOCK=128
//   M = B*T = 16384 rows
//   GEMM1: [16384,1024] @ [1024,3072] -> qkv
//   attn : 2048 blocks of (128x64) q,k,v, causal-within-block softmax
//   GEMM2: [16384,1024] @ [1024,1024] + bias -> out (fp32)

typedef __bf16 bf16_t;
typedef __bf16 bf16x8 __attribute__((ext_vector_type(8)));
typedef float  f32x4  __attribute__((ext_vector_type(4)));

typedef const __attribute__((address_space(1))) void* gptr_t;
typedef __attribute__((address_space(3))) void* lptr_t;

// ---------------------------------------------------------------- cvt: f32 -> bf16
__global__ __launch_bounds__(256) void cvt_f32_bf16(const float* __restrict__ in,
                                                    bf16_t* __restrict__ out, size_t n) {
    size_t stride = (size_t)gridDim.x * blockDim.x * 4;
    for (size_t i = ((size_t)blockIdx.x * blockDim.x + threadIdx.x) * 4; i < n; i += stride) {
        float4 v = *(const float4*)(in + i);
        bf16_t t[4];
        t[0] = (bf16_t)v.x; t[1] = (bf16_t)v.y; t[2] = (bf16_t)v.z; t[3] = (bf16_t)v.w;
        *(uint2*)(out + i) = *(uint2*)t;
    }
}

// ------------------------------- transpose+cvt: W[K][N] fp32 -> Wt[N][K] bf16, LDS-tiled
__global__ __launch_bounds__(256) void transpose_cvt(const float* __restrict__ in,
                                                     bf16_t* __restrict__ out, int K, int N) {
    __shared__ float tile[32][33];
    const int tx = threadIdx.x & 31, ty = threadIdx.x >> 5;   // 32 x 8
    const int bx = blockIdx.x, by = blockIdx.y;               // N/32, K/32
    #pragma unroll
    for (int i = 0; i < 4; i++) {
        const int k = by * 32 + ty + i * 8;
        tile[ty + i * 8][tx] = in[(size_t)k * N + bx * 32 + tx];
    }
    __syncthreads();
    #pragma unroll
    for (int i = 0; i < 4; i++) {
        const int n = bx * 32 + ty + i * 8;
        out[(size_t)n * K + by * 32 + tx] = (bf16_t)tile[tx][ty + i * 8];
    }
}

// ---------------------------------------------------------------- GEMM (B-transposed)
// C[M][N] = A[M][K] * Bt[N][K]^T   (bf16 in, fp32 accum)
// 256x256 tile, 8 waves (2Mx4N), ring of 4 K=32 slices per matrix (128 KiB LDS).
// T3+T4 done right this time: fine per-phase interleave (m196) AND counted vmcnt
// (m218). Each slice = 2 phases:
//   A: 8 ds_read_b128 (af0-3,bf0-3) | 2 global_load_lds (A-half, slice ks+3)
//      -> s_barrier -> lgkmcnt(0) -> setprio(1) 16 MFMA setprio(0) -> s_barrier
//   B: 4 ds_read_b128 (af4-7)      | 2 global_load_lds (B-half)
//      -> vmcnt(8)  [slice ks+1 lands; never 0 until 3-slice peeled tail]
//      -> s_barrier -> lgkmcnt(0) -> setprio(1) 16 MFMA setprio(0) -> s_barrier
// ds_reads issue BEFORE the opening barrier (latency hides under barrier wait;
// data guaranteed by previous slice's vmcnt+barrier). Slot hazard: stage target
// (ks+3)&3 == (ks-1)&3, fully read + retired before slice ks-1's closing barrier.
// LDS swizzle (rule 21, both-sides): 16B chunk ^= (row>>1)&3 on the pre-swizzled
// GLOBAL source addr (LDS dest stays linear) and on the ds_read addr.
template <bool BF16_OUT, bool BIAS>
__global__ __launch_bounds__(512, 2) void gemm256(const bf16_t* __restrict__ A,
                                                  const bf16_t* __restrict__ Bt,
                                                  void* __restrict__ Cout,
                                                  const float* __restrict__ bias,
                                                  int M, int N, int K) {
    __shared__ bf16_t As[4][256 * 32];   // ring slot s: rows 0..255, K-slice of 32
    __shared__ bf16_t Bs[4][256 * 32];

    const int tid  = threadIdx.x;
    const int lane = tid & 63, wave = tid >> 6;
    const int quad = lane >> 4, l16 = lane & 15;
    const int wm = wave >> 2, wn = wave & 3;   // 2 x 4 wave grid; wave owns 128x64 of C
    const int bn = blockIdx.x, bm = blockIdx.y;

    const bf16_t* Ab = A  + (size_t)bm * 256 * K;
    const bf16_t* Bb = Bt + (size_t)bn * 256 * K;

    // staging geometry: wave-load = 16 rows x 64B; lane -> (row = l>>2, chunk = l&3)
    const int srow = lane >> 2;
    const int scs  = (lane & 3) ^ ((srow >> 1) & 3);   // pre-swizzled src chunk
    const int rdo  = ((quad ^ ((l16 >> 1) & 3)) << 3); // read-side swizzled elem offset

    f32x4 acc[8][4];
    #pragma unroll
    for (int i = 0; i < 8; ++i)
        #pragma unroll
        for (int j = 0; j < 4; ++j) acc[i][j] = (f32x4){0.f, 0.f, 0.f, 0.f};

#define STG(ARR, SRC, SLICE, I)                                                       \
    __builtin_amdgcn_global_load_lds(                                                 \
        (gptr_t)((SRC) + (size_t)(wave * 32 + (I) * 16 + srow) * K + ((SLICE) << 5) + \
                 scs * 8),                                                            \
        (lptr_t)&(ARR)[(SLICE) & 3][(wave * 32 + (I) * 16) * 32], 16, 0, 0)

#define SLICE_BODY(KS, DO_STAGE, WAIT_STMT)                                           \
    do {                                                                              \
        const int ks_ = (KS);                                                         \
        const bf16_t* Asl_ = As[ks_ & 3];                                             \
        const bf16_t* Bsl_ = Bs[ks_ & 3];                                             \
        bf16x8 af_[8], bf_[4];                                                        \
        /* ---- phase A: 8 reads + A-half stage + 16 MFMA ---- */                     \
        _Pragma("unroll")                                                             \
        for (int fr = 0; fr < 4; ++fr)                                                \
            af_[fr] = *(const bf16x8*)&Asl_[(wm * 128 + fr * 16 + l16) * 32 + rdo];   \
        _Pragma("unroll")                                                             \
        for (int fr = 0; fr < 4; ++fr)                                                \
            bf_[fr] = *(const bf16x8*)&Bsl_[(wn * 64 + fr * 16 + l16) * 32 + rdo];    \
        if (DO_STAGE) { STG(As, Ab, ks_ + 3, 0); STG(As, Ab, ks_ + 3, 1); }           \
        __builtin_amdgcn_s_barrier();                                                 \
        asm volatile("s_waitcnt lgkmcnt(0)" ::: "memory");                            \
        __builtin_amdgcn_s_setprio(1);                                                \
        _Pragma("unroll")                                                             \
        for (int mr = 0; mr < 4; ++mr)                                                \
            _Pragma("unroll")                                                         \
            for (int nr = 0; nr < 4; ++nr)                                            \
                acc[mr][nr] = __builtin_amdgcn_mfma_f32_16x16x32_bf16(                \
                    af_[mr], bf_[nr], acc[mr][nr], 0, 0, 0);                          \
        __builtin_amdgcn_s_setprio(0);                                                \
        __builtin_amdgcn_s_barrier();                                                 \
        /* ---- phase B: 4 reads + B-half stage + counted wait + 16 MFMA ---- */      \
        _Pragma("unroll")                                                             \
        for (int fr = 0; fr < 4; ++fr)                                                \
            af_[4 + fr] =                                                             \
                *(const bf16x8*)&Asl_[(wm * 128 + (4 + fr) * 16 + l16) * 32 + rdo];   \
        if (DO_STAGE) { STG(Bs, Bb, ks_ + 3, 0); STG(Bs, Bb, ks_ + 3, 1); }           \
        WAIT_STMT;                                                                    \
        __builtin_amdgcn_s_barrier();                                                 \
        asm volatile("s_waitcnt lgkmcnt(0)" ::: "memory");                            \
        __builtin_amdgcn_s_setprio(1);                                                \
        _Pragma("unroll")                                                             \
        for (int mr = 0; mr < 4; ++mr)                                                \
            _Pragma("unroll")                                                         \
            for (int nr = 0; nr < 4; ++nr)                                            \
                acc[4 + mr][nr] = __builtin_amdgcn_mfma_f32_16x16x32_bf16(            \
                    af_[4 + mr], bf_[nr], acc[4 + mr][nr], 0, 0, 0);                  \
        __builtin_amdgcn_s_setprio(0);                                                \
        __builtin_amdgcn_s_barrier();                                                 \
    } while (0)

    // prologue: stage slices 0,1,2 (groups of 4 loads per slice, in slice order)
    STG(As, Ab, 0, 0); STG(As, Ab, 0, 1); STG(Bs, Bb, 0, 0); STG(Bs, Bb, 0, 1);
    STG(As, Ab, 1, 0); STG(As, Ab, 1, 1); STG(Bs, Bb, 1, 0); STG(Bs, Bb, 1, 1);
    STG(As, Ab, 2, 0); STG(As, Ab, 2, 1); STG(Bs, Bb, 2, 0); STG(Bs, Bb, 2, 1);
    asm volatile("s_waitcnt vmcnt(8)" ::: "memory");   // slice 0 landed
    __builtin_amdgcn_s_barrier();

    const int NS = K >> 5;   // K=1024 -> 32 slices
    for (int ks = 0; ks < NS - 3; ++ks)
        SLICE_BODY(ks, true, asm volatile("s_waitcnt vmcnt(8)" ::: "memory"));
    // tail: the only place vmcnt drains toward 0
    SLICE_BODY(NS - 3, false, asm volatile("s_waitcnt vmcnt(4)" ::: "memory"));
    SLICE_BODY(NS - 2, false, asm volatile("s_waitcnt vmcnt(0)" ::: "memory"));
    SLICE_BODY(NS - 1, false, (void)0);
#undef SLICE_BODY
#undef STG

    // epilogue: C/D layout col=lane&15, row=quad*4+reg
    #pragma unroll
    for (int mr = 0; mr < 8; ++mr) {
        #pragma unroll
        for (int nr = 0; nr < 4; ++nr) {
            const int gcol = bn * 256 + wn * 64 + nr * 16 + l16;
            #pragma unroll
            for (int reg = 0; reg < 4; ++reg) {
                const int grow = bm * 256 + wm * 128 + mr * 16 + quad * 4 + reg;
                float v = acc[mr][nr][reg];
                if (BIAS) v += bias[gcol];
                if (BF16_OUT)
                    ((bf16_t*)Cout)[(size_t)grow * N + gcol] = (bf16_t)v;
                else
                    ((float*)Cout)[(size_t)grow * N + gcol] = v;
            }
        }
    }
}

// ---------------------------------------------------------------- block-local attention
// One workgroup per (b, blk, h). q,k: [128][72] LDS; v stored TRANSPOSED [64][136] so
// PV B-fragments are ds_read_b128. LDS total 54272 B -> 3 blocks/CU.
__global__ __launch_bounds__(256, 3) void attn_kernel(const bf16_t* __restrict__ qkv,
                                                      bf16_t* __restrict__ attn_out) {
    __shared__ __align__(16) char smem[54272];
    bf16_t* qs = (bf16_t*)smem;                   // [128][72]
    bf16_t* ks = (bf16_t*)(smem + 18432);         // [128][72]
    bf16_t* vT = (bf16_t*)(smem + 36864);         // [64][136]  vT[c][r] = v[r][c]
    bf16_t* ps = (bf16_t*)smem;                   // [128][136] overlays qs+ks (34816 <= 36864)

    const int tid = threadIdx.x;
    const int lane = tid & 63, wave = tid >> 6;
    const int quad = lane >> 4, l16 = lane & 15;

    const int bid = blockIdx.x;
    const int h = bid & 15;
    const int blk = (bid >> 4) & 31;
    const int b = bid >> 9;
    const int row0 = (b * 32 + blk) * 128;   // row base in [16384]
    const int LDQ = 3072;

    // ---- stage q,k (vector), v transposed (scalar scatter, one-time)
    for (int t = tid; t < 128 * 8; t += 256) {
        const int r = t >> 3;
        const int c = (t & 7) * 8;           // element offset
        const bf16_t* src = qkv + (size_t)(row0 + r) * LDQ + h * 64;
        *(uint4*)&qs[r * 72 + c] = *(const uint4*)(src + c);
        *(uint4*)&ks[r * 72 + c] = *(const uint4*)(src + 1024 + c);
        bf16x8 vv = *(const bf16x8*)(src + 2048 + c);
        #pragma unroll
        for (int j = 0; j < 8; j++)
            vT[(c + j) * 136 + r] = vv[j];
    }
    __syncthreads();

    // ---- S = q k^T / 8 : wave handles rows [wave*32, wave*32+32) x 128 cols
    f32x4 sfrag[2][8];
    for (int mr = 0; mr < 2; mr++)
        for (int nc = 0; nc < 8; nc++)
            sfrag[mr][nc] = (f32x4){0.f, 0.f, 0.f, 0.f};

    #pragma unroll
    for (int ksl = 0; ksl < 2; ksl++) {     // K=64 in two slices of 32
        bf16x8 aq[2], bk[8];
        #pragma unroll
        for (int mr = 0; mr < 2; mr++)
            aq[mr] = *(const bf16x8*)&qs[(wave * 32 + mr * 16 + l16) * 72 + ksl * 32 + quad * 8];
        #pragma unroll
        for (int nc = 0; nc < 8; nc++)
            bk[nc] = *(const bf16x8*)&ks[(nc * 16 + l16) * 72 + ksl * 32 + quad * 8];
        #pragma unroll
        for (int mr = 0; mr < 2; mr++)
            #pragma unroll
            for (int nc = 0; nc < 8; nc++)
                sfrag[mr][nc] = __builtin_amdgcn_mfma_f32_16x16x32_bf16(aq[mr], bk[nc], sfrag[mr][nc], 0, 0, 0);
    }

    // ---- scale + causal mask (C-layout: row=quad*4+reg, col=nc*16+l16)
    #pragma unroll
    for (int mr = 0; mr < 2; mr++) {
        #pragma unroll
        for (int nc = 0; nc < 8; nc++) {
            #pragma unroll
            for (int reg = 0; reg < 4; reg++) {
                const int row = wave * 32 + mr * 16 + quad * 4 + reg;
                const int col = nc * 16 + l16;
                float s = sfrag[mr][nc][reg] * 0.125f;
                if (col > row) s = -INFINITY;
                sfrag[mr][nc][reg] = s;
            }
        }
    }

    // ---- softmax per row (reduce across 16 lanes of the row-group + 8 col frags)
    #pragma unroll
    for (int mr = 0; mr < 2; mr++) {
        #pragma unroll
        for (int reg = 0; reg < 4; reg++) {
            float m = -INFINITY;
            #pragma unroll
            for (int nc = 0; nc < 8; nc++) m = fmaxf(m, sfrag[mr][nc][reg]);
            #pragma unroll
            for (int off = 1; off < 16; off <<= 1) m = fmaxf(m, __shfl_xor(m, off));
            float sum = 0.f;
            #pragma unroll
            for (int nc = 0; nc < 8; nc++) {
                float e = __expf(sfrag[mr][nc][reg] - m);
                sfrag[mr][nc][reg] = e;
                sum += e;
            }
            #pragma unroll
            for (int off = 1; off < 16; off <<= 1) sum += __shfl_xor(sum, off);
            const float inv = 1.0f / (sum + 1e-6f);
            #pragma unroll
            for (int nc = 0; nc < 8; nc++) sfrag[mr][nc][reg] *= inv;
        }
    }

    __syncthreads();   // all waves done reading qs/ks before P overlays them

    // ---- write P (bf16) to LDS [128][136]
    #pragma unroll
    for (int mr = 0; mr < 2; mr++)
        #pragma unroll
        for (int nc = 0; nc < 8; nc++)
            #pragma unroll
            for (int reg = 0; reg < 4; reg++) {
                const int row = wave * 32 + mr * 16 + quad * 4 + reg;
                const int col = nc * 16 + l16;
                ps[row * 136 + col] = (bf16_t)sfrag[mr][nc][reg];
            }
    __syncthreads();

    // ---- O = P @ V : rows [wave*32, +32) x 64 cols, K=128 in 4 slices; V from vT (b128)
    f32x4 oacc[2][4];
    for (int mr = 0; mr < 2; mr++)
        for (int nd = 0; nd < 4; nd++)
            oacc[mr][nd] = (f32x4){0.f, 0.f, 0.f, 0.f};

    #pragma unroll
    for (int ksl = 0; ksl < 4; ksl++) {
        bf16x8 ap[2];
        #pragma unroll
        for (int mr = 0; mr < 2; mr++)
            ap[mr] = *(const bf16x8*)&ps[(wave * 32 + mr * 16 + l16) * 136 + ksl * 32 + quad * 8];
        #pragma unroll
        for (int nd = 0; nd < 4; nd++) {
            bf16x8 bv = *(const bf16x8*)&vT[(nd * 16 + l16) * 136 + ksl * 32 + quad * 8];
            #pragma unroll
            for (int mr = 0; mr < 2; mr++)
                oacc[mr][nd] = __builtin_amdgcn_mfma_f32_16x16x32_bf16(ap[mr], bv, oacc[mr][nd], 0, 0, 0);
        }
    }

    // ---- store O bf16 into attn buffer [16384][1024]
    #pragma unroll
    for (int mr = 0; mr < 2; mr++)
        #pragma unroll
        for (int nd = 0; nd < 4; nd++)
            #pragma unroll
            for (int reg = 0; reg < 4; reg++) {
                const int row = row0 + wave * 32 + mr * 16 + quad * 4 + reg;
                const int col = h * 64 + nd * 16 + l16;
                attn_out[(size_t)row * 1024 + col] = (bf16_t)oacc[mr][nd][reg];
            }
}

// ---------------------------------------------------------------- launch
extern "C" void kernel_launch(void* const* d_in, const int* in_sizes, int n_in,
                              void* d_out, int out_size, void* d_ws, size_t ws_size,
                              hipStream_t stream) {
    const float* x     = (const float*)d_in[0];   // [4,4096,1024]
    const float* Wqkv  = (const float*)d_in[1];   // [1024,3072]
    const float* Wproj = (const float*)d_in[2];   // [1024,1024]
    const float* bproj = (const float*)d_in[3];   // [1024]

    const int M = 16384, C = 1024, N1 = 3072;

    // workspace carve (bytes): all 16B aligned
    char* ws = (char*)d_ws;
    bf16_t* xb     = (bf16_t*)(ws);                                   // 32 MB
    bf16_t* wqkvT  = (bf16_t*)(ws + 33554432);                        //  6 MB  [3072][1024]
    bf16_t* wprojT = (bf16_t*)(ws + 39845888);                        //  2 MB  [1024][1024]
    bf16_t* qkvb   = (bf16_t*)(ws + 41943040);                        // 96 MB  [16384][3072]
    bf16_t* attnb  = (bf16_t*)(ws + 142606336);                       // 32 MB  [16384][1024]
    // total 168 MB

    cvt_f32_bf16<<<8192, 256, 0, stream>>>(x, xb, (size_t)M * C);
    transpose_cvt<<<dim3(N1 / 32, C / 32), 256, 0, stream>>>(Wqkv, wqkvT, C, N1);
    transpose_cvt<<<dim3(C / 32, C / 32), 256, 0, stream>>>(Wproj, wprojT, C, C);

    gemm256<true, false><<<dim3(N1 / 256, M / 256), 512, 0, stream>>>(
        xb, wqkvT, (void*)qkvb, nullptr, M, N1, C);

    attn_kernel<<<2048, 256, 0, stream>>>(qkvb, attnb);

    gemm256<false, true><<<dim3(C / 256, M / 256), 512, 0, stream>>>(
        attnb, wprojT, d_out, bproj, M, C, C);
}

// Round 4
// 316.358 us; speedup vs baseline: 1.0981x; 1.0169x over previous
//
#include <hip/hip_runtime.h>
#include <hip/hip_bf16.h>
#include <math.h>

// Problem constants: B=4, T=4096, C=1024, H=16, D=64, BLOCK=128
//   M = B*T = 16384 rows
//   GEMM1: [16384,1024] @ [1024,3072] -> qkv
//   attn : 2048 blocks of (128x64) q,k,v, causal-within-block softmax
//   GEMM2: [16384,1024] @ [1024,1024] + bias -> out (fp32)

typedef __bf16 bf16_t;
typedef __bf16 bf16x8 __attribute__((ext_vector_type(8)));
typedef float  f32x4  __attribute__((ext_vector_type(4)));

typedef const __attribute__((address_space(1))) void* gptr_t;
typedef __attribute__((address_space(3))) void* lptr_t;

// ---------------------------------------------------------------- cvt: f32 -> bf16
__global__ __launch_bounds__(256) void cvt_f32_bf16(const float* __restrict__ in,
                                                    bf16_t* __restrict__ out, size_t n) {
    size_t stride = (size_t)gridDim.x * blockDim.x * 4;
    for (size_t i = ((size_t)blockIdx.x * blockDim.x + threadIdx.x) * 4; i < n; i += stride) {
        float4 v = *(const float4*)(in + i);
        bf16_t t[4];
        t[0] = (bf16_t)v.x; t[1] = (bf16_t)v.y; t[2] = (bf16_t)v.z; t[3] = (bf16_t)v.w;
        *(uint2*)(out + i) = *(uint2*)t;
    }
}

// ------------------------------- transpose+cvt: W[K][N] fp32 -> Wt[N][K] bf16, LDS-tiled
__global__ __launch_bounds__(256) void transpose_cvt(const float* __restrict__ in,
                                                     bf16_t* __restrict__ out, int K, int N) {
    __shared__ float tile[32][33];
    const int tx = threadIdx.x & 31, ty = threadIdx.x >> 5;   // 32 x 8
    const int bx = blockIdx.x, by = blockIdx.y;               // N/32, K/32
    #pragma unroll
    for (int i = 0; i < 4; i++) {
        const int k = by * 32 + ty + i * 8;
        tile[ty + i * 8][tx] = in[(size_t)k * N + bx * 32 + tx];
    }
    __syncthreads();
    #pragma unroll
    for (int i = 0; i < 4; i++) {
        const int n = bx * 32 + ty + i * 8;
        out[(size_t)n * K + by * 32 + tx] = (bf16_t)tile[tx][ty + i * 8];
    }
}

// ---------------------------------------------------------------- GEMM (B-transposed)
// C[M][N] = A[M][K] * Bt[N][K]^T   (bf16 in, fp32 accum)
// 256x256 tile, 8 waves (2Mx4N), ring of 4 K=32 slices per matrix (128 KiB LDS).
// Inner schedule identical to round 3 (verified): per slice 2 phases, fine
// ds_read | global_load_lds interleave, counted vmcnt(8), setprio around MFMA.
//
// NEW (round 4): XCD-chunked tile swizzle (T1). Theory: staging traffic is
// 768 blocks x 1 MB = 768 MB/dispatch; default round-robin dispatch mixes all
// (bm,bn) across XCDs so the per-XCD working set (~38 MB) thrashes the 4 MB L2
// and panel re-reads are served by L3 (~6.5 TB/s -> ~118 us = the whole kernel).
// Remap: xcd = blockIdx.x & 7 owns a contiguous strip of 8 bm rows; within the
// strip bn-outer/bm-inner, so concurrent working set = 8 A-panels (4 MB, becomes
// L2-resident, re-read 12x from L2) + ~4 B-panels (2 MB). Requires nwg % 8 == 0
// and (M/256) % 8 == 0: GEMM1 768 = 8x96, GEMM2 256 = 8x32, M/256 = 64. OK.
template <bool BF16_OUT, bool BIAS>
__global__ __launch_bounds__(512, 2) void gemm256(const bf16_t* __restrict__ A,
                                                  const bf16_t* __restrict__ Bt,
                                                  void* __restrict__ Cout,
                                                  const float* __restrict__ bias,
                                                  int M, int N, int K) {
    __shared__ bf16_t As[4][256 * 32];   // ring slot s: rows 0..255, K-slice of 32
    __shared__ bf16_t Bs[4][256 * 32];

    const int tid  = threadIdx.x;
    const int lane = tid & 63, wave = tid >> 6;
    const int quad = lane >> 4, l16 = lane & 15;
    const int wm = wave >> 2, wn = wave & 3;   // 2 x 4 wave grid; wave owns 128x64 of C

    // ---- XCD-chunked swizzle: each XCD gets bm strip [xcd*mloc, (xcd+1)*mloc)
    const int nbm  = M >> 8;              // # of bm tiles (64)
    const int mloc = nbm >> 3;            // bm tiles per XCD strip (8)
    const int xcd  = blockIdx.x & 7;
    const int idx  = blockIdx.x >> 3;     // 0 .. nwg/8-1
    const int bn   = idx / mloc;          // bn-outer
    const int bm   = xcd * mloc + (idx - bn * mloc);   // bm-inner within strip

    const bf16_t* Ab = A  + (size_t)bm * 256 * K;
    const bf16_t* Bb = Bt + (size_t)bn * 256 * K;

    // staging geometry: wave-load = 16 rows x 64B; lane -> (row = l>>2, chunk = l&3)
    const int srow = lane >> 2;
    const int scs  = (lane & 3) ^ ((srow >> 1) & 3);   // pre-swizzled src chunk
    const int rdo  = ((quad ^ ((l16 >> 1) & 3)) << 3); // read-side swizzled elem offset

    f32x4 acc[8][4];
    #pragma unroll
    for (int i = 0; i < 8; ++i)
        #pragma unroll
        for (int j = 0; j < 4; ++j) acc[i][j] = (f32x4){0.f, 0.f, 0.f, 0.f};

#define STG(ARR, SRC, SLICE, I)                                                       \
    __builtin_amdgcn_global_load_lds(                                                 \
        (gptr_t)((SRC) + (size_t)(wave * 32 + (I) * 16 + srow) * K + ((SLICE) << 5) + \
                 scs * 8),                                                            \
        (lptr_t)&(ARR)[(SLICE) & 3][(wave * 32 + (I) * 16) * 32], 16, 0, 0)

#define SLICE_BODY(KS, DO_STAGE, WAIT_STMT)                                           \
    do {                                                                              \
        const int ks_ = (KS);                                                         \
        const bf16_t* Asl_ = As[ks_ & 3];                                             \
        const bf16_t* Bsl_ = Bs[ks_ & 3];                                             \
        bf16x8 af_[8], bf_[4];                                                        \
        /* ---- phase A: 8 reads + A-half stage + 16 MFMA ---- */                     \
        _Pragma("unroll")                                                             \
        for (int fr = 0; fr < 4; ++fr)                                                \
            af_[fr] = *(const bf16x8*)&Asl_[(wm * 128 + fr * 16 + l16) * 32 + rdo];   \
        _Pragma("unroll")                                                             \
        for (int fr = 0; fr < 4; ++fr)                                                \
            bf_[fr] = *(const bf16x8*)&Bsl_[(wn * 64 + fr * 16 + l16) * 32 + rdo];    \
        if (DO_STAGE) { STG(As, Ab, ks_ + 3, 0); STG(As, Ab, ks_ + 3, 1); }           \
        __builtin_amdgcn_s_barrier();                                                 \
        asm volatile("s_waitcnt lgkmcnt(0)" ::: "memory");                            \
        __builtin_amdgcn_s_setprio(1);                                                \
        _Pragma("unroll")                                                             \
        for (int mr = 0; mr < 4; ++mr)                                                \
            _Pragma("unroll")                                                         \
            for (int nr = 0; nr < 4; ++nr)                                            \
                acc[mr][nr] = __builtin_amdgcn_mfma_f32_16x16x32_bf16(                \
                    af_[mr], bf_[nr], acc[mr][nr], 0, 0, 0);                          \
        __builtin_amdgcn_s_setprio(0);                                                \
        __builtin_amdgcn_s_barrier();                                                 \
        /* ---- phase B: 4 reads + B-half stage + counted wait + 16 MFMA ---- */      \
        _Pragma("unroll")                                                             \
        for (int fr = 0; fr < 4; ++fr)                                                \
            af_[4 + fr] =                                                             \
                *(const bf16x8*)&Asl_[(wm * 128 + (4 + fr) * 16 + l16) * 32 + rdo];   \
        if (DO_STAGE) { STG(Bs, Bb, ks_ + 3, 0); STG(Bs, Bb, ks_ + 3, 1); }           \
        WAIT_STMT;                                                                    \
        __builtin_amdgcn_s_barrier();                                                 \
        asm volatile("s_waitcnt lgkmcnt(0)" ::: "memory");                            \
        __builtin_amdgcn_s_setprio(1);                                                \
        _Pragma("unroll")                                                             \
        for (int mr = 0; mr < 4; ++mr)                                                \
            _Pragma("unroll")                                                         \
            for (int nr = 0; nr < 4; ++nr)                                            \
                acc[4 + mr][nr] = __builtin_amdgcn_mfma_f32_16x16x32_bf16(            \
                    af_[4 + mr], bf_[nr], acc[4 + mr][nr], 0, 0, 0);                  \
        __builtin_amdgcn_s_setprio(0);                                                \
        __builtin_amdgcn_s_barrier();                                                 \
    } while (0)

    // prologue: stage slices 0,1,2 (groups of 4 loads per slice, in slice order)
    STG(As, Ab, 0, 0); STG(As, Ab, 0, 1); STG(Bs, Bb, 0, 0); STG(Bs, Bb, 0, 1);
    STG(As, Ab, 1, 0); STG(As, Ab, 1, 1); STG(Bs, Bb, 1, 0); STG(Bs, Bb, 1, 1);
    STG(As, Ab, 2, 0); STG(As, Ab, 2, 1); STG(Bs, Bb, 2, 0); STG(Bs, Bb, 2, 1);
    asm volatile("s_waitcnt vmcnt(8)" ::: "memory");   // slice 0 landed
    __builtin_amdgcn_s_barrier();

    const int NS = K >> 5;   // K=1024 -> 32 slices
    for (int ks = 0; ks < NS - 3; ++ks)
        SLICE_BODY(ks, true, asm volatile("s_waitcnt vmcnt(8)" ::: "memory"));
    // tail: the only place vmcnt drains toward 0
    SLICE_BODY(NS - 3, false, asm volatile("s_waitcnt vmcnt(4)" ::: "memory"));
    SLICE_BODY(NS - 2, false, asm volatile("s_waitcnt vmcnt(0)" ::: "memory"));
    SLICE_BODY(NS - 1, false, (void)0);
#undef SLICE_BODY
#undef STG

    // epilogue: C/D layout col=lane&15, row=quad*4+reg
    #pragma unroll
    for (int mr = 0; mr < 8; ++mr) {
        #pragma unroll
        for (int nr = 0; nr < 4; ++nr) {
            const int gcol = bn * 256 + wn * 64 + nr * 16 + l16;
            #pragma unroll
            for (int reg = 0; reg < 4; ++reg) {
                const int grow = bm * 256 + wm * 128 + mr * 16 + quad * 4 + reg;
                float v = acc[mr][nr][reg];
                if (BIAS) v += bias[gcol];
                if (BF16_OUT)
                    ((bf16_t*)Cout)[(size_t)grow * N + gcol] = (bf16_t)v;
                else
                    ((float*)Cout)[(size_t)grow * N + gcol] = v;
            }
        }
    }
}

// ---------------------------------------------------------------- block-local attention
// One workgroup per (b, blk, h). q,k: [128][72] LDS; v stored TRANSPOSED [64][136] so
// PV B-fragments are ds_read_b128. LDS total 54272 B -> 3 blocks/CU.
__global__ __launch_bounds__(256, 3) void attn_kernel(const bf16_t* __restrict__ qkv,
                                                      bf16_t* __restrict__ attn_out) {
    __shared__ __align__(16) char smem[54272];
    bf16_t* qs = (bf16_t*)smem;                   // [128][72]
    bf16_t* ks = (bf16_t*)(smem + 18432);         // [128][72]
    bf16_t* vT = (bf16_t*)(smem + 36864);         // [64][136]  vT[c][r] = v[r][c]
    bf16_t* ps = (bf16_t*)smem;                   // [128][136] overlays qs+ks (34816 <= 36864)

    const int tid = threadIdx.x;
    const int lane = tid & 63, wave = tid >> 6;
    const int quad = lane >> 4, l16 = lane & 15;

    const int bid = blockIdx.x;
    const int h = bid & 15;
    const int blk = (bid >> 4) & 31;
    const int b = bid >> 9;
    const int row0 = (b * 32 + blk) * 128;   // row base in [16384]
    const int LDQ = 3072;

    // ---- stage q,k (vector), v transposed (scalar scatter, one-time)
    for (int t = tid; t < 128 * 8; t += 256) {
        const int r = t >> 3;
        const int c = (t & 7) * 8;           // element offset
        const bf16_t* src = qkv + (size_t)(row0 + r) * LDQ + h * 64;
        *(uint4*)&qs[r * 72 + c] = *(const uint4*)(src + c);
        *(uint4*)&ks[r * 72 + c] = *(const uint4*)(src + 1024 + c);
        bf16x8 vv = *(const bf16x8*)(src + 2048 + c);
        #pragma unroll
        for (int j = 0; j < 8; j++)
            vT[(c + j) * 136 + r] = vv[j];
    }
    __syncthreads();

    // ---- S = q k^T / 8 : wave handles rows [wave*32, wave*32+32) x 128 cols
    f32x4 sfrag[2][8];
    for (int mr = 0; mr < 2; mr++)
        for (int nc = 0; nc < 8; nc++)
            sfrag[mr][nc] = (f32x4){0.f, 0.f, 0.f, 0.f};

    #pragma unroll
    for (int ksl = 0; ksl < 2; ksl++) {     // K=64 in two slices of 32
        bf16x8 aq[2], bk[8];
        #pragma unroll
        for (int mr = 0; mr < 2; mr++)
            aq[mr] = *(const bf16x8*)&qs[(wave * 32 + mr * 16 + l16) * 72 + ksl * 32 + quad * 8];
        #pragma unroll
        for (int nc = 0; nc < 8; nc++)
            bk[nc] = *(const bf16x8*)&ks[(nc * 16 + l16) * 72 + ksl * 32 + quad * 8];
        #pragma unroll
        for (int mr = 0; mr < 2; mr++)
            #pragma unroll
            for (int nc = 0; nc < 8; nc++)
                sfrag[mr][nc] = __builtin_amdgcn_mfma_f32_16x16x32_bf16(aq[mr], bk[nc], sfrag[mr][nc], 0, 0, 0);
    }

    // ---- scale + causal mask (C-layout: row=quad*4+reg, col=nc*16+l16)
    #pragma unroll
    for (int mr = 0; mr < 2; mr++) {
        #pragma unroll
        for (int nc = 0; nc < 8; nc++) {
            #pragma unroll
            for (int reg = 0; reg < 4; reg++) {
                const int row = wave * 32 + mr * 16 + quad * 4 + reg;
                const int col = nc * 16 + l16;
                float s = sfrag[mr][nc][reg] * 0.125f;
                if (col > row) s = -INFINITY;
                sfrag[mr][nc][reg] = s;
            }
        }
    }

    // ---- softmax per row (reduce across 16 lanes of the row-group + 8 col frags)
    #pragma unroll
    for (int mr = 0; mr < 2; mr++) {
        #pragma unroll
        for (int reg = 0; reg < 4; reg++) {
            float m = -INFINITY;
            #pragma unroll
            for (int nc = 0; nc < 8; nc++) m = fmaxf(m, sfrag[mr][nc][reg]);
            #pragma unroll
            for (int off = 1; off < 16; off <<= 1) m = fmaxf(m, __shfl_xor(m, off));
            float sum = 0.f;
            #pragma unroll
            for (int nc = 0; nc < 8; nc++) {
                float e = __expf(sfrag[mr][nc][reg] - m);
                sfrag[mr][nc][reg] = e;
                sum += e;
            }
            #pragma unroll
            for (int off = 1; off < 16; off <<= 1) sum += __shfl_xor(sum, off);
            const float inv = 1.0f / (sum + 1e-6f);
            #pragma unroll
            for (int nc = 0; nc < 8; nc++) sfrag[mr][nc][reg] *= inv;
        }
    }

    __syncthreads();   // all waves done reading qs/ks before P overlays them

    // ---- write P (bf16) to LDS [128][136]
    #pragma unroll
    for (int mr = 0; mr < 2; mr++)
        #pragma unroll
        for (int nc = 0; nc < 8; nc++)
            #pragma unroll
            for (int reg = 0; reg < 4; reg++) {
                const int row = wave * 32 + mr * 16 + quad * 4 + reg;
                const int col = nc * 16 + l16;
                ps[row * 136 + col] = (bf16_t)sfrag[mr][nc][reg];
            }
    __syncthreads();

    // ---- O = P @ V : rows [wave*32, +32) x 64 cols, K=128 in 4 slices; V from vT (b128)
    f32x4 oacc[2][4];
    for (int mr = 0; mr < 2; mr++)
        for (int nd = 0; nd < 4; nd++)
            oacc[mr][nd] = (f32x4){0.f, 0.f, 0.f, 0.f};

    #pragma unroll
    for (int ksl = 0; ksl < 4; ksl++) {
        bf16x8 ap[2];
        #pragma unroll
        for (int mr = 0; mr < 2; mr++)
            ap[mr] = *(const bf16x8*)&ps[(wave * 32 + mr * 16 + l16) * 136 + ksl * 32 + quad * 8];
        #pragma unroll
        for (int nd = 0; nd < 4; nd++) {
            bf16x8 bv = *(const bf16x8*)&vT[(nd * 16 + l16) * 136 + ksl * 32 + quad * 8];
            #pragma unroll
            for (int mr = 0; mr < 2; mr++)
                oacc[mr][nd] = __builtin_amdgcn_mfma_f32_16x16x32_bf16(ap[mr], bv, oacc[mr][nd], 0, 0, 0);
        }
    }

    // ---- store O bf16 into attn buffer [16384][1024]
    #pragma unroll
    for (int mr = 0; mr < 2; mr++)
        #pragma unroll
        for (int nd = 0; nd < 4; nd++)
            #pragma unroll
            for (int reg = 0; reg < 4; reg++) {
                const int row = row0 + wave * 32 + mr * 16 + quad * 4 + reg;
                const int col = h * 64 + nd * 16 + l16;
                attn_out[(size_t)row * 1024 + col] = (bf16_t)oacc[mr][nd][reg];
            }
}

// ---------------------------------------------------------------- launch
extern "C" void kernel_launch(void* const* d_in, const int* in_sizes, int n_in,
                              void* d_out, int out_size, void* d_ws, size_t ws_size,
                              hipStream_t stream) {
    const float* x     = (const float*)d_in[0];   // [4,4096,1024]
    const float* Wqkv  = (const float*)d_in[1];   // [1024,3072]
    const float* Wproj = (const float*)d_in[2];   // [1024,1024]
    const float* bproj = (const float*)d_in[3];   // [1024]

    const int M = 16384, C = 1024, N1 = 3072;

    // workspace carve (bytes): all 16B aligned
    char* ws = (char*)d_ws;
    bf16_t* xb     = (bf16_t*)(ws);                                   // 32 MB
    bf16_t* wqkvT  = (bf16_t*)(ws + 33554432);                        //  6 MB  [3072][1024]
    bf16_t* wprojT = (bf16_t*)(ws + 39845888);                        //  2 MB  [1024][1024]
    bf16_t* qkvb   = (bf16_t*)(ws + 41943040);                        // 96 MB  [16384][3072]
    bf16_t* attnb  = (bf16_t*)(ws + 142606336);                       // 32 MB  [16384][1024]
    // total 168 MB

    cvt_f32_bf16<<<8192, 256, 0, stream>>>(x, xb, (size_t)M * C);
    transpose_cvt<<<dim3(N1 / 32, C / 32), 256, 0, stream>>>(Wqkv, wqkvT, C, N1);
    transpose_cvt<<<dim3(C / 32, C / 32), 256, 0, stream>>>(Wproj, wprojT, C, C);

    // 1D grids, XCD-chunk-swizzled in-kernel: 768 = 8*96, 256 = 8*32
    gemm256<true, false><<<(N1 / 256) * (M / 256), 512, 0, stream>>>(
        xb, wqkvT, (void*)qkvb, nullptr, M, N1, C);

    attn_kernel<<<2048, 256, 0, stream>>>(qkvb, attnb);

    gemm256<false, true><<<(C / 256) * (M / 256), 512, 0, stream>>>(
        attnb, wprojT, d_out, bproj, M, C, C);
}